// Round 8
// baseline (121.980 us; speedup 1.0000x reference)
//
#include <hip/hip_runtime.h>

#define N_NODES 50000
#define N_PAD   50048        // padded node count (tail reads defined, store guarded)
#define N_EDGES 600000
#define IN_F 128
#define HID 256
#define OUT_F 64
#define ROWS 16              // nodes per block; N_PAD/16 = 3128 blocks
#define SLOTS 56             // fixed bucket slots/node; P(deg>=56|Poisson(12))~1e-24
#define NBLK (N_PAD / ROWS)
#define EPT 4                // edges per thread in build (4 atomic chains in flight)

typedef __attribute__((ext_vector_type(8))) short bf16x8;
typedef __attribute__((ext_vector_type(4))) float f32x4;

__device__ inline short f2bf(float f) {   // RNE float->bf16 bits
    unsigned u = __builtin_bit_cast(unsigned, f);
    u += 0x7fffu + ((u >> 16) & 1u);
    return (short)(u >> 16);
}
__device__ inline float bflo(unsigned u) { return __builtin_bit_cast(float, u << 16); }
__device__ inline float bfhi(unsigned u) { return __builtin_bit_cast(float, u & 0xffff0000u); }

// ---------------------------------------------------------------------------
// build: fixed-stride bucket fill, 4 edges/thread (independent atomic chains).
// Runs FIRST and ALONE — atomics must not contend with streaming converts
// (round-6/7 lesson: merged = 67-71 us, separate = ~20 us).
// cursor (pre-zeroed) ends up as deg.
// ---------------------------------------------------------------------------
__global__ __launch_bounds__(256) void build_kernel(
    const int* __restrict__ ei, int* __restrict__ cursor,
    unsigned short* __restrict__ esrc)
{
    int t0 = blockIdx.x * (256 * EPT) + threadIdx.x;
    int src[EPT], dst[EPT], p[EPT];
    bool v[EPT];
    #pragma unroll
    for (int i = 0; i < EPT; ++i) {
        int e = t0 + i * 256;
        v[i] = e < N_EDGES;
        int ee = v[i] ? e : 0;
        src[i] = ei[ee];
        dst[i] = ei[N_EDGES + ee];
    }
    #pragma unroll
    for (int i = 0; i < EPT; ++i)
        p[i] = v[i] ? atomicAdd(&cursor[dst[i]], 1) : SLOTS;
    #pragma unroll
    for (int i = 0; i < EPT; ++i)
        if (v[i] && p[i] < SLOTS)
            esrc[(size_t)dst[i] * SLOTS + p[i]] = (unsigned short)src[i];
}

// ---------------------------------------------------------------------------
// prep: convert x -> bf16 and weights -> bf16 B-fragment-major chunks.
//   [0,3125)      x fp32 -> bf16
//   [3125,3173)   12288 weight chunks: F1a, F1b, Fc (= bf16(Wsg@W2a), computed
//                 inline in fp32), F2b
// chunk c: lane=c&63, ks=(c>>6)%KST, nt=(c>>6)/KST;
//   elem j: B[ks*32 + (lane>>4)*8 + j][nt*16 + (lane&15)]
// ---------------------------------------------------------------------------
__global__ __launch_bounds__(256) void prep_kernel(
    const float* __restrict__ x, short* __restrict__ xb,
    const float* __restrict__ Wsg, const float* __restrict__ W2a,
    const float* __restrict__ W1a, const float* __restrict__ W1b,
    const float* __restrict__ W2b,
    short* __restrict__ F1a, short* __restrict__ F1b,
    short* __restrict__ Fc,  short* __restrict__ F2b)
{
    const int bid = blockIdx.x, t = threadIdx.x;
    if (bid < 3125) {
        int i = bid * 256 + t;                       // < 800000 exactly
        float4 a0 = *reinterpret_cast<const float4*>(x + (size_t)i * 8);
        float4 a1 = *reinterpret_cast<const float4*>(x + (size_t)i * 8 + 4);
        bf16x8 v;
        v[0] = f2bf(a0.x); v[1] = f2bf(a0.y); v[2] = f2bf(a0.z); v[3] = f2bf(a0.w);
        v[4] = f2bf(a1.x); v[5] = f2bf(a1.y); v[6] = f2bf(a1.z); v[7] = f2bf(a1.w);
        *reinterpret_cast<bf16x8*>(xb + (size_t)i * 8) = v;
        return;
    }
    int cid = (bid - 3125) * 256 + t;                // < 12288 exactly
    if (cid >= 6144 && cid < 10240) {
        // Fc chunk: Wc = Wsg @ W2a computed in fp32, then bf16 fragment
        int c = cid - 6144;
        int lane = c & 63, rem = c >> 6;
        int ks = rem & 3, nt = rem >> 2;
        int col = nt * 16 + (lane & 15);
        int k0 = ks * 32 + (lane >> 4) * 8;
        float acc[8] = {0.f, 0.f, 0.f, 0.f, 0.f, 0.f, 0.f, 0.f};
        for (int m0 = 0; m0 < 128; m0 += 8) {
            float wcol[8];
            #pragma unroll
            for (int mm = 0; mm < 8; ++mm)
                wcol[mm] = W2a[(size_t)(m0 + mm) * HID + col];
            #pragma unroll
            for (int j = 0; j < 8; ++j) {
                #pragma unroll
                for (int mm = 0; mm < 8; ++mm)
                    acc[j] = fmaf(Wsg[(size_t)(k0 + j) * IN_F + m0 + mm], wcol[mm], acc[j]);
            }
        }
        bf16x8 v;
        #pragma unroll
        for (int j = 0; j < 8; ++j) v[j] = f2bf(acc[j]);
        *reinterpret_cast<bf16x8*>(Fc + (size_t)c * 8) = v;
    } else {
        const float* src; short* dst; int N, KST, base;
        if      (cid < 4096)  { src = W1a; dst = F1a; N = 256; KST = 4; base = 0; }
        else if (cid < 6144)  { src = W1b; dst = F1b; N = 64;  KST = 8; base = 4096; }
        else                  { src = W2b; dst = F2b; N = 64;  KST = 8; base = 10240; }
        int c = cid - base;
        int lane = c & 63;
        int rem = c >> 6;
        int ks = rem % KST;
        int nt = rem / KST;
        int col = nt * 16 + (lane & 15);
        int k0 = ks * 32 + (lane >> 4) * 8;
        bf16x8 v;
        #pragma unroll
        for (int j = 0; j < 8; ++j)
            v[j] = f2bf(src[(size_t)(k0 + j) * N + col]);
        *reinterpret_cast<bf16x8*>(dst + (size_t)c * 8) = v;
    }
}

// ---------------------------------------------------------------------------
// LDS tile helpers: [16][C] bf16 with 16B-chunk XOR swizzle (chunk ^= row)
// ---------------------------------------------------------------------------
__device__ inline bf16x8 afrag_lds128(const short* S, int lane, int ks) {
    int row = lane & 15, g = lane >> 4;
    int chunk = (ks * 4 + g) ^ row;            // 0..15
    return *reinterpret_cast<const bf16x8*>(
        reinterpret_cast<const char*>(S) + row * 256 + chunk * 16);
}
__device__ inline bf16x8 afrag_lds256(const short* S, int lane, int ks) {
    int row = lane & 15, g = lane >> 4;
    int chunk = (ks * 4 + g) ^ row;            // XOR flips low 4 bits, 0..31
    return *reinterpret_cast<const bf16x8*>(
        reinterpret_cast<const char*>(S) + row * 512 + chunk * 16);
}

// ---------------------------------------------------------------------------
// MFMA stages (16-row tile, 4 waves). setprio(1) around MFMA clusters:
// resident blocks sit at different phases (gather vs MFMA) -> T5 regime.
// stage1: Hs = relu(A @ Wa + ba) -> 16x256 bf16 swizzled LDS; wave w: nt=4w..4w+3
// stage2: acc += Hs(16x256) @ Wb(256x64); wave w: col-tile nt=w
// ---------------------------------------------------------------------------
__device__ inline void stage1_relu(const bf16x8 afr[4], short* Hs,
                                   const short* __restrict__ Waf,
                                   const float* __restrict__ ba,
                                   int w, int lane)
{
    const int row16 = lane & 15, g = lane >> 4;
    #pragma unroll
    for (int i = 0; i < 4; ++i) {
        int nt = w * 4 + i;
        f32x4 acc = {0.f, 0.f, 0.f, 0.f};
        __builtin_amdgcn_s_setprio(1);
        #pragma unroll
        for (int ks = 0; ks < 4; ++ks) {
            bf16x8 b = *reinterpret_cast<const bf16x8*>(
                Waf + ((size_t)(nt * 4 + ks) * 64 + lane) * 8);
            acc = __builtin_amdgcn_mfma_f32_16x16x32_bf16(afr[ks], b, acc, 0, 0, 0);
        }
        __builtin_amdgcn_s_setprio(0);
        int col = nt * 16 + row16;
        float bias = ba[col];
        #pragma unroll
        for (int reg = 0; reg < 4; ++reg) {
            int hrow = g * 4 + reg;
            float v = fmaxf(acc[reg] + bias, 0.0f);
            *reinterpret_cast<short*>(reinterpret_cast<char*>(Hs)
                + hrow * 512 + ((((col >> 3) ^ hrow) & 31) * 16) + (col & 7) * 2) = f2bf(v);
        }
    }
}

__device__ inline f32x4 stage2_acc(const short* Hs, const short* __restrict__ Wbf,
                                   int w, int lane, f32x4 acc)
{
    __builtin_amdgcn_s_setprio(1);
    #pragma unroll
    for (int ks = 0; ks < 8; ++ks) {
        bf16x8 a = afrag_lds256(Hs, lane, ks);
        bf16x8 b = *reinterpret_cast<const bf16x8*>(
            Wbf + ((size_t)(w * 8 + ks) * 64 + lane) * 8);
        acc = __builtin_amdgcn_mfma_f32_16x16x32_bf16(a, b, acc, 0, 0, 0);
    }
    __builtin_amdgcn_s_setprio(0);
    return acc;
}

// ---------------------------------------------------------------------------
// Fused kernel (16 rows/block, 4 waves, LDS 12 KB):
//   gather-mean -> Ms
//   oacc  = stage2(relu(Ms @ Wc + b2a), W2b)        [SAGE GEMM folded into Wc]
//   oacc += stage2(relu(x  @ W1a + b1a), W1b)
//   out = oacc + b1b + b2b   (single guarded store)
// ---------------------------------------------------------------------------
__global__ __launch_bounds__(256) void fused_kernel(
    const short* __restrict__ xb, const unsigned short* __restrict__ esrc,
    const int* __restrict__ deg,
    const short* __restrict__ F1a, const float* __restrict__ b1a,
    const short* __restrict__ F1b, const float* __restrict__ b1b,
    const short* __restrict__ Fc,  const float* __restrict__ b2a,
    const short* __restrict__ F2b, const float* __restrict__ b2b,
    float* __restrict__ out)
{
    __shared__ short Ms[16 * 128];   // 4 KB
    __shared__ short Hs[16 * 256];   // 8 KB
    const int t = threadIdx.x, w = t >> 6, lane = t & 63;
    const long r0 = (long)blockIdx.x * ROWS;
    const int row16 = lane & 15, g = lane >> 4;

    // ---- gather-mean: wave w owns rows w*4..+3; lane owns 2 features.
    //      16 row-loads in flight per chunk; ushort indices. ----
    #pragma unroll
    for (int nn = 0; nn < 4; ++nn) {
        int row = w * 4 + nn;
        long node = r0 + row;
        int d = deg[node]; d = min(d, SLOTS);
        int slot = min(lane, SLOTS - 1);
        int my = esrc[(size_t)node * SLOTS + slot];     // coalesced 2B/lane
        float ax = 0.f, ay = 0.f;
        for (int j = 0; j < d; j += 16) {
            unsigned u[16];
            #pragma unroll
            for (int k = 0; k < 16; ++k) {
                int cidx = min(j + k, d - 1);            // clamp: dup last row
                int s = __builtin_amdgcn_readlane(my, cidx);
                u[k] = *reinterpret_cast<const unsigned*>(xb + (size_t)s * IN_F + lane * 2);
            }
            #pragma unroll
            for (int k = 0; k < 16; ++k) {
                float wk = (j + k < d) ? 1.0f : 0.0f;    // mask padded dups
                ax = fmaf(bflo(u[k]), wk, ax);
                ay = fmaf(bfhi(u[k]), wk, ay);
            }
        }
        float inv = (d > 0) ? 1.0f / (float)d : 0.0f;
        ax *= inv; ay *= inv;
        int chunk = (lane >> 2) ^ row;                   // XOR swizzle
        unsigned packed = (unsigned)(unsigned short)f2bf(ax)
                        | ((unsigned)(unsigned short)f2bf(ay) << 16);
        *reinterpret_cast<unsigned*>(reinterpret_cast<char*>(Ms)
            + row * 256 + chunk * 16 + (lane & 3) * 4) = packed;
    }
    __syncthreads();

    // ---- branch 2 stage 1: Hs = relu(Ms @ Wc + b2a) ----
    {
        bf16x8 afr[4];
        #pragma unroll
        for (int ks = 0; ks < 4; ++ks) afr[ks] = afrag_lds128(Ms, lane, ks);
        stage1_relu(afr, Hs, Fc, b2a, w, lane);
    }
    __syncthreads();

    // ---- branch 2 stage 2 -> register accumulator ----
    f32x4 oacc = {0.f, 0.f, 0.f, 0.f};
    oacc = stage2_acc(Hs, F2b, w, lane, oacc);
    __syncthreads();                                     // before Hs overwrite

    // ---- branch 1 stage 1: Hs = relu(x @ W1a + b1a), A-frags from global xb ----
    {
        bf16x8 afr[4];
        const short* xrow = xb + (size_t)(r0 + row16) * IN_F + g * 8;
        #pragma unroll
        for (int ks = 0; ks < 4; ++ks)
            afr[ks] = *reinterpret_cast<const bf16x8*>(xrow + ks * 32);
        stage1_relu(afr, Hs, F1a, b1a, w, lane);
    }
    __syncthreads();

    // ---- branch 1 stage 2 + single guarded store ----
    oacc = stage2_acc(Hs, F1b, w, lane, oacc);
    {
        int col = w * 16 + row16;
        float bias = b1b[col] + b2b[col];
        #pragma unroll
        for (int reg = 0; reg < 4; ++reg) {
            long row = r0 + g * 4 + reg;
            if (row < N_NODES)
                out[row * OUT_F + col] = oacc[reg] + bias;
        }
    }
}

// ---------------------------------------------------------------------------
extern "C" void kernel_launch(void* const* d_in, const int* in_sizes, int n_in,
                              void* d_out, int out_size, void* d_ws, size_t ws_size,
                              hipStream_t stream)
{
    const float* x   = (const float*)d_in[0];
    const int*   ei  = (const int*)d_in[1];
    const float* Wsg = (const float*)d_in[2];
    const float* W1a = (const float*)d_in[3];
    const float* b1a = (const float*)d_in[4];
    const float* W1b = (const float*)d_in[5];
    const float* b1b = (const float*)d_in[6];
    const float* W2a = (const float*)d_in[7];
    const float* b2a = (const float*)d_in[8];
    const float* W2b = (const float*)d_in[9];
    const float* b2b = (const float*)d_in[10];
    float* out = (float*)d_out;

    // workspace layout (all 16B-aligned): ~18.8 MB total
    int* cursor = (int*)d_ws;                              // [N_PAD] (200 KB)
    unsigned short* esrc = (unsigned short*)(cursor + N_PAD);  // [N_PAD*56] = 5.6 MB
    short* F1a = (short*)(esrc + (size_t)N_PAD * SLOTS);   // 4096 chunks (64 KB)
    short* F1b = F1a + 4096 * 8;                           // 2048 chunks (32 KB)
    short* Fc  = F1b + 2048 * 8;                           // 4096 chunks (64 KB)
    short* F2b = Fc + 4096 * 8;                            // 2048 chunks (32 KB)
    short* xb  = F2b + 2048 * 8;                           // [N_PAD*128] bf16 (12.8 MB)

    hipMemsetAsync(cursor, 0, N_PAD * sizeof(int), stream);
    build_kernel<<<(N_EDGES + 256 * EPT - 1) / (256 * EPT), 256, 0, stream>>>(
        ei, cursor, esrc);
    prep_kernel<<<3173, 256, 0, stream>>>(x, xb, Wsg, W2a, W1a, W1b, W2b,
                                          F1a, F1b, Fc, F2b);
    fused_kernel<<<NBLK, 256, 0, stream>>>(xb, esrc, cursor,
                                           F1a, b1a, F1b, b1b,
                                           Fc, b2a, F2b, b2b, out);
}

// Round 9
// 114.957 us; speedup vs baseline: 1.0611x; 1.0611x over previous
//
#include <hip/hip_runtime.h>

#define N_NODES 50000
#define N_PAD   50048        // padded node count (tail reads defined, store guarded)
#define N_EDGES 600000
#define IN_F 128
#define HID 256
#define OUT_F 64
#define ROWS 16              // nodes per block; N_PAD/16 = 3128 blocks
#define SLOTS 56             // fixed bucket slots/node; P(deg>=56|Poisson(12))~1e-24
#define NBLK (N_PAD / ROWS)

typedef __attribute__((ext_vector_type(8))) short bf16x8;
typedef __attribute__((ext_vector_type(4))) float f32x4;

__device__ inline short f2bf(float f) {   // RNE float->bf16 bits
    unsigned u = __builtin_bit_cast(unsigned, f);
    u += 0x7fffu + ((u >> 16) & 1u);
    return (short)(u >> 16);
}
__device__ inline float bflo(unsigned u) { return __builtin_bit_cast(float, u << 16); }
__device__ inline float bfhi(unsigned u) { return __builtin_bit_cast(float, u & 0xffff0000u); }

// ---------------------------------------------------------------------------
// prep: convert x -> bf16, weights -> bf16 B-fragment-major chunks, zero cursor.
//   [0,3125)      x fp32 -> bf16
//   [3125,3173)   12288 weight chunks: F1a, F1b, Fc (= bf16(Wsg@W2a), fp32
//                 inline GEMM), F2b
//   [3173,3200)   zero cursor
// chunk c: lane=c&63, ks=(c>>6)%KST, nt=(c>>6)/KST;
//   elem j: B[ks*32 + (lane>>4)*8 + j][nt*16 + (lane&15)]
// ---------------------------------------------------------------------------
__global__ __launch_bounds__(256) void prep_kernel(
    const float* __restrict__ x, short* __restrict__ xb,
    const float* __restrict__ Wsg, const float* __restrict__ W2a,
    const float* __restrict__ W1a, const float* __restrict__ W1b,
    const float* __restrict__ W2b,
    short* __restrict__ F1a, short* __restrict__ F1b,
    short* __restrict__ Fc,  short* __restrict__ F2b,
    int* __restrict__ cursor)
{
    const int bid = blockIdx.x, t = threadIdx.x;
    if (bid < 3125) {
        int i = bid * 256 + t;                       // < 800000 exactly
        float4 a0 = *reinterpret_cast<const float4*>(x + (size_t)i * 8);
        float4 a1 = *reinterpret_cast<const float4*>(x + (size_t)i * 8 + 4);
        bf16x8 v;
        v[0] = f2bf(a0.x); v[1] = f2bf(a0.y); v[2] = f2bf(a0.z); v[3] = f2bf(a0.w);
        v[4] = f2bf(a1.x); v[5] = f2bf(a1.y); v[6] = f2bf(a1.z); v[7] = f2bf(a1.w);
        *reinterpret_cast<bf16x8*>(xb + (size_t)i * 8) = v;
        return;
    }
    if (bid >= 3173) {
        for (int i = (bid - 3173) * 256 + t; i < N_PAD; i += 27 * 256)
            cursor[i] = 0;
        return;
    }
    int cid = (bid - 3125) * 256 + t;                // < 12288 exactly
    if (cid >= 6144 && cid < 10240) {
        // Fc chunk: Wc = Wsg @ W2a computed in fp32, then bf16 fragment
        int c = cid - 6144;
        int lane = c & 63, rem = c >> 6;
        int ks = rem & 3, nt = rem >> 2;
        int col = nt * 16 + (lane & 15);
        int k0 = ks * 32 + (lane >> 4) * 8;
        float acc[8] = {0.f, 0.f, 0.f, 0.f, 0.f, 0.f, 0.f, 0.f};
        for (int m0 = 0; m0 < 128; m0 += 8) {
            float wcol[8];
            #pragma unroll
            for (int mm = 0; mm < 8; ++mm)
                wcol[mm] = W2a[(size_t)(m0 + mm) * HID + col];
            #pragma unroll
            for (int j = 0; j < 8; ++j) {
                #pragma unroll
                for (int mm = 0; mm < 8; ++mm)
                    acc[j] = fmaf(Wsg[(size_t)(k0 + j) * IN_F + m0 + mm], wcol[mm], acc[j]);
            }
        }
        bf16x8 v;
        #pragma unroll
        for (int j = 0; j < 8; ++j) v[j] = f2bf(acc[j]);
        *reinterpret_cast<bf16x8*>(Fc + (size_t)c * 8) = v;
    } else {
        const float* src; short* dst; int N, KST, base;
        if      (cid < 4096)  { src = W1a; dst = F1a; N = 256; KST = 4; base = 0; }
        else if (cid < 6144)  { src = W1b; dst = F1b; N = 64;  KST = 8; base = 4096; }
        else                  { src = W2b; dst = F2b; N = 64;  KST = 8; base = 10240; }
        int c = cid - base;
        int lane = c & 63;
        int rem = c >> 6;
        int ks = rem % KST;
        int nt = rem / KST;
        int col = nt * 16 + (lane & 15);
        int k0 = ks * 32 + (lane >> 4) * 8;
        bf16x8 v;
        #pragma unroll
        for (int j = 0; j < 8; ++j)
            v[j] = f2bf(src[(size_t)(k0 + j) * N + col]);
        *reinterpret_cast<bf16x8*>(dst + (size_t)c * 8) = v;
    }
}

// ---------------------------------------------------------------------------
// build: fixed-stride bucket fill, 1 edge/thread (max thread-level parallelism
// for the latency-bound atomics — round-8 EPT=4 regressed). Runs alone:
// merging with streaming converts cost 2-3x (round-7 lesson).
// cursor (zeroed by prep) ends up as deg.
// ---------------------------------------------------------------------------
__global__ __launch_bounds__(256) void build_kernel(
    const int* __restrict__ ei, int* __restrict__ cursor,
    unsigned short* __restrict__ esrc)
{
    int e = blockIdx.x * 256 + threadIdx.x;
    if (e >= N_EDGES) return;
    int src = ei[e];
    int dst = ei[N_EDGES + e];
    int p = atomicAdd(&cursor[dst], 1);
    if (p < SLOTS) esrc[(size_t)dst * SLOTS + p] = (unsigned short)src;
}

// ---------------------------------------------------------------------------
// LDS tile helpers: [16][C] bf16 with 16B-chunk XOR swizzle (chunk ^= row)
// ---------------------------------------------------------------------------
__device__ inline bf16x8 afrag_lds128(const short* S, int lane, int ks) {
    int row = lane & 15, g = lane >> 4;
    int chunk = (ks * 4 + g) ^ row;            // 0..15
    return *reinterpret_cast<const bf16x8*>(
        reinterpret_cast<const char*>(S) + row * 256 + chunk * 16);
}
__device__ inline bf16x8 afrag_lds256(const short* S, int lane, int ks) {
    int row = lane & 15, g = lane >> 4;
    int chunk = (ks * 4 + g) ^ row;            // XOR flips low 4 bits, 0..31
    return *reinterpret_cast<const bf16x8*>(
        reinterpret_cast<const char*>(S) + row * 512 + chunk * 16);
}

// ---------------------------------------------------------------------------
// MFMA stages (16-row tile, 4 waves)
// stage1: Hs = relu(A @ Wa + ba) -> 16x256 bf16 swizzled LDS; wave w: nt=4w..4w+3
// stage2: acc += Hs(16x256) @ Wb(256x64); wave w: col-tile nt=w
// ---------------------------------------------------------------------------
__device__ inline void stage1_relu(const bf16x8 afr[4], short* Hs,
                                   const short* __restrict__ Waf,
                                   const float* __restrict__ ba,
                                   int w, int lane)
{
    const int row16 = lane & 15, g = lane >> 4;
    #pragma unroll
    for (int i = 0; i < 4; ++i) {
        int nt = w * 4 + i;
        f32x4 acc = {0.f, 0.f, 0.f, 0.f};
        #pragma unroll
        for (int ks = 0; ks < 4; ++ks) {
            bf16x8 b = *reinterpret_cast<const bf16x8*>(
                Waf + ((size_t)(nt * 4 + ks) * 64 + lane) * 8);
            acc = __builtin_amdgcn_mfma_f32_16x16x32_bf16(afr[ks], b, acc, 0, 0, 0);
        }
        int col = nt * 16 + row16;
        float bias = ba[col];
        #pragma unroll
        for (int reg = 0; reg < 4; ++reg) {
            int hrow = g * 4 + reg;
            float v = fmaxf(acc[reg] + bias, 0.0f);
            *reinterpret_cast<short*>(reinterpret_cast<char*>(Hs)
                + hrow * 512 + ((((col >> 3) ^ hrow) & 31) * 16) + (col & 7) * 2) = f2bf(v);
        }
    }
}

__device__ inline f32x4 stage2_acc(const short* Hs, const short* __restrict__ Wbf,
                                   int w, int lane, f32x4 acc)
{
    #pragma unroll
    for (int ks = 0; ks < 8; ++ks) {
        bf16x8 a = afrag_lds256(Hs, lane, ks);
        bf16x8 b = *reinterpret_cast<const bf16x8*>(
            Wbf + ((size_t)(w * 8 + ks) * 64 + lane) * 8);
        acc = __builtin_amdgcn_mfma_f32_16x16x32_bf16(a, b, acc, 0, 0, 0);
    }
    return acc;
}

// ---------------------------------------------------------------------------
// Fused kernel (16 rows/block, 4 waves, LDS 12 KB):
//   gather-mean (node-PAIR interleaved: 32 row-loads in flight) -> Ms
//   oacc  = stage2(relu(Ms @ Wc + b2a), W2b)        [SAGE GEMM folded into Wc]
//   oacc += stage2(relu(x  @ W1a + b1a), W1b)
//   out = oacc + b1b + b2b   (single guarded store)
// ---------------------------------------------------------------------------
__global__ __launch_bounds__(256) void fused_kernel(
    const short* __restrict__ xb, const unsigned short* __restrict__ esrc,
    const int* __restrict__ deg,
    const short* __restrict__ F1a, const float* __restrict__ b1a,
    const short* __restrict__ F1b, const float* __restrict__ b1b,
    const short* __restrict__ Fc,  const float* __restrict__ b2a,
    const short* __restrict__ F2b, const float* __restrict__ b2b,
    float* __restrict__ out)
{
    __shared__ short Ms[16 * 128];   // 4 KB
    __shared__ short Hs[16 * 256];   // 8 KB
    const int t = threadIdx.x, w = t >> 6, lane = t & 63;
    const long r0 = (long)blockIdx.x * ROWS;
    const int row16 = lane & 15, g = lane >> 4;

    // ---- gather-mean: wave w owns rows w*4..+3, processed as 2 node-pairs.
    //      Per pair: issue A's 16 + B's 16 row-loads (32 in flight, 8 KB),
    //      then accumulate A (waits half), then B. ----
    #pragma unroll 1
    for (int p = 0; p < 2; ++p) {
        int rowA = w * 4 + p * 2;
        int rowB = rowA + 1;
        long nodeA = r0 + rowA, nodeB = r0 + rowB;
        int dA = min(deg[nodeA], SLOTS);
        int dB = min(deg[nodeB], SLOTS);
        int slot = min(lane, SLOTS - 1);
        int myA = esrc[(size_t)nodeA * SLOTS + slot];   // coalesced 2B/lane
        int myB = esrc[(size_t)nodeB * SLOTS + slot];
        int cA = max(dA - 1, 0), cB = max(dB - 1, 0);
        int dmax = max(dA, dB);
        float axA = 0.f, ayA = 0.f, axB = 0.f, ayB = 0.f;
        for (int j = 0; j < dmax; j += 16) {
            unsigned ua[16], ub[16];
            #pragma unroll
            for (int k = 0; k < 16; ++k) {
                int s = __builtin_amdgcn_readlane(myA, min(j + k, cA));
                ua[k] = *reinterpret_cast<const unsigned*>(xb + (size_t)s * IN_F + lane * 2);
            }
            #pragma unroll
            for (int k = 0; k < 16; ++k) {
                int s = __builtin_amdgcn_readlane(myB, min(j + k, cB));
                ub[k] = *reinterpret_cast<const unsigned*>(xb + (size_t)s * IN_F + lane * 2);
            }
            #pragma unroll
            for (int k = 0; k < 16; ++k) {              // waits only A's loads
                float wk = (j + k < dA) ? 1.0f : 0.0f;
                axA = fmaf(bflo(ua[k]), wk, axA);
                ayA = fmaf(bfhi(ua[k]), wk, ayA);
            }
            #pragma unroll
            for (int k = 0; k < 16; ++k) {
                float wk = (j + k < dB) ? 1.0f : 0.0f;
                axB = fmaf(bflo(ub[k]), wk, axB);
                ayB = fmaf(bfhi(ub[k]), wk, ayB);
            }
        }
        float invA = (dA > 0) ? 1.0f / (float)dA : 0.0f;
        float invB = (dB > 0) ? 1.0f / (float)dB : 0.0f;
        unsigned pkA = (unsigned)(unsigned short)f2bf(axA * invA)
                     | ((unsigned)(unsigned short)f2bf(ayA * invA) << 16);
        unsigned pkB = (unsigned)(unsigned short)f2bf(axB * invB)
                     | ((unsigned)(unsigned short)f2bf(ayB * invB) << 16);
        int chA = (lane >> 2) ^ rowA;                   // XOR swizzle
        int chB = (lane >> 2) ^ rowB;
        *reinterpret_cast<unsigned*>(reinterpret_cast<char*>(Ms)
            + rowA * 256 + chA * 16 + (lane & 3) * 4) = pkA;
        *reinterpret_cast<unsigned*>(reinterpret_cast<char*>(Ms)
            + rowB * 256 + chB * 16 + (lane & 3) * 4) = pkB;
    }
    __syncthreads();

    // ---- branch 2 stage 1: Hs = relu(Ms @ Wc + b2a) ----
    {
        bf16x8 afr[4];
        #pragma unroll
        for (int ks = 0; ks < 4; ++ks) afr[ks] = afrag_lds128(Ms, lane, ks);
        stage1_relu(afr, Hs, Fc, b2a, w, lane);
    }
    __syncthreads();

    // ---- branch 2 stage 2 -> register accumulator ----
    f32x4 oacc = {0.f, 0.f, 0.f, 0.f};
    oacc = stage2_acc(Hs, F2b, w, lane, oacc);
    __syncthreads();                                     // before Hs overwrite

    // ---- branch 1 stage 1: Hs = relu(x @ W1a + b1a), A-frags from global xb ----
    {
        bf16x8 afr[4];
        const short* xrow = xb + (size_t)(r0 + row16) * IN_F + g * 8;
        #pragma unroll
        for (int ks = 0; ks < 4; ++ks)
            afr[ks] = *reinterpret_cast<const bf16x8*>(xrow + ks * 32);
        stage1_relu(afr, Hs, F1a, b1a, w, lane);
    }
    __syncthreads();

    // ---- branch 1 stage 2 + single guarded store ----
    oacc = stage2_acc(Hs, F1b, w, lane, oacc);
    {
        int col = w * 16 + row16;
        float bias = b1b[col] + b2b[col];
        #pragma unroll
        for (int reg = 0; reg < 4; ++reg) {
            long row = r0 + g * 4 + reg;
            if (row < N_NODES)
                out[row * OUT_F + col] = oacc[reg] + bias;
        }
    }
}

// ---------------------------------------------------------------------------
extern "C" void kernel_launch(void* const* d_in, const int* in_sizes, int n_in,
                              void* d_out, int out_size, void* d_ws, size_t ws_size,
                              hipStream_t stream)
{
    const float* x   = (const float*)d_in[0];
    const int*   ei  = (const int*)d_in[1];
    const float* Wsg = (const float*)d_in[2];
    const float* W1a = (const float*)d_in[3];
    const float* b1a = (const float*)d_in[4];
    const float* W1b = (const float*)d_in[5];
    const float* b1b = (const float*)d_in[6];
    const float* W2a = (const float*)d_in[7];
    const float* b2a = (const float*)d_in[8];
    const float* W2b = (const float*)d_in[9];
    const float* b2b = (const float*)d_in[10];
    float* out = (float*)d_out;

    // workspace layout (all 16B-aligned): ~18.8 MB total
    int* cursor = (int*)d_ws;                              // [N_PAD] (200 KB)
    unsigned short* esrc = (unsigned short*)(cursor + N_PAD);  // [N_PAD*56] = 5.6 MB
    short* F1a = (short*)(esrc + (size_t)N_PAD * SLOTS);   // 4096 chunks (64 KB)
    short* F1b = F1a + 4096 * 8;                           // 2048 chunks (32 KB)
    short* Fc  = F1b + 2048 * 8;                           // 4096 chunks (64 KB)
    short* F2b = Fc + 4096 * 8;                            // 2048 chunks (32 KB)
    short* xb  = F2b + 2048 * 8;                           // [N_PAD*128] bf16 (12.8 MB)

    prep_kernel<<<3200, 256, 0, stream>>>(x, xb, Wsg, W2a, W1a, W1b, W2b,
                                          F1a, F1b, Fc, F2b, cursor);
    build_kernel<<<(N_EDGES + 255) / 256, 256, 0, stream>>>(ei, cursor, esrc);
    fused_kernel<<<NBLK, 256, 0, stream>>>(xb, esrc, cursor,
                                           F1a, b1a, F1b, b1b,
                                           Fc, b2a, F2b, b2b, out);
}

// Round 10
// 108.089 us; speedup vs baseline: 1.1285x; 1.0635x over previous
//
#include <hip/hip_runtime.h>

#define N_NODES 50000
#define N_PAD   50048        // padded node count (tail reads defined, store guarded)
#define N_EDGES 600000
#define IN_F 128
#define HID 256
#define OUT_F 64
#define ROWS 16              // nodes per block; N_PAD/16 = 3128 blocks
#define SLOTS 56             // fixed bucket slots/node; P(deg>=56|Poisson(12))~1e-24
#define NBLK (N_PAD / ROWS)
#define ZERO_ROW N_NODES     // xb row 50000 is zeroed; padded gather slots read it

typedef __attribute__((ext_vector_type(8))) short bf16x8;
typedef __attribute__((ext_vector_type(4))) float f32x4;

__device__ inline short f2bf(float f) {   // RNE float->bf16 bits
    unsigned u = __builtin_bit_cast(unsigned, f);
    u += 0x7fffu + ((u >> 16) & 1u);
    return (short)(u >> 16);
}
__device__ inline float bflo(unsigned u) { return __builtin_bit_cast(float, u << 16); }
__device__ inline float bfhi(unsigned u) { return __builtin_bit_cast(float, u & 0xffff0000u); }

// ---------------------------------------------------------------------------
// prep: convert x -> bf16, weights -> bf16 B-fragment-major chunks, zero
// cursor, zero the xb pad rows (incl. ZERO_ROW used for gather padding).
//   [0,3125)      x fp32 -> bf16
//   [3125,3173)   12288 weight chunks: F1a, F1b, Fc (= bf16(Wsg@W2a), fp32
//                 inline GEMM), F2b
//   [3173,3200)   zero cursor
//   [3200,3203)   zero xb rows 50000..50047 (768 16B chunks)
// chunk c: lane=c&63, ks=(c>>6)%KST, nt=(c>>6)/KST;
//   elem j: B[ks*32 + (lane>>4)*8 + j][nt*16 + (lane&15)]
// ---------------------------------------------------------------------------
__global__ __launch_bounds__(256) void prep_kernel(
    const float* __restrict__ x, short* __restrict__ xb,
    const float* __restrict__ Wsg, const float* __restrict__ W2a,
    const float* __restrict__ W1a, const float* __restrict__ W1b,
    const float* __restrict__ W2b,
    short* __restrict__ F1a, short* __restrict__ F1b,
    short* __restrict__ Fc,  short* __restrict__ F2b,
    int* __restrict__ cursor)
{
    const int bid = blockIdx.x, t = threadIdx.x;
    if (bid < 3125) {
        int i = bid * 256 + t;                       // < 800000 exactly
        float4 a0 = *reinterpret_cast<const float4*>(x + (size_t)i * 8);
        float4 a1 = *reinterpret_cast<const float4*>(x + (size_t)i * 8 + 4);
        bf16x8 v;
        v[0] = f2bf(a0.x); v[1] = f2bf(a0.y); v[2] = f2bf(a0.z); v[3] = f2bf(a0.w);
        v[4] = f2bf(a1.x); v[5] = f2bf(a1.y); v[6] = f2bf(a1.z); v[7] = f2bf(a1.w);
        *reinterpret_cast<bf16x8*>(xb + (size_t)i * 8) = v;
        return;
    }
    if (bid >= 3200) {
        int i = (bid - 3200) * 256 + t;              // < 768 exactly
        bf16x8 z = {0, 0, 0, 0, 0, 0, 0, 0};
        *reinterpret_cast<bf16x8*>(xb + (size_t)N_NODES * IN_F + (size_t)i * 8) = z;
        return;
    }
    if (bid >= 3173) {
        for (int i = (bid - 3173) * 256 + t; i < N_PAD; i += 27 * 256)
            cursor[i] = 0;
        return;
    }
    int cid = (bid - 3125) * 256 + t;                // < 12288 exactly
    if (cid >= 6144 && cid < 10240) {
        // Fc chunk: Wc = Wsg @ W2a computed in fp32, then bf16 fragment
        int c = cid - 6144;
        int lane = c & 63, rem = c >> 6;
        int ks = rem & 3, nt = rem >> 2;
        int col = nt * 16 + (lane & 15);
        int k0 = ks * 32 + (lane >> 4) * 8;
        float acc[8] = {0.f, 0.f, 0.f, 0.f, 0.f, 0.f, 0.f, 0.f};
        for (int m0 = 0; m0 < 128; m0 += 8) {
            float wcol[8];
            #pragma unroll
            for (int mm = 0; mm < 8; ++mm)
                wcol[mm] = W2a[(size_t)(m0 + mm) * HID + col];
            #pragma unroll
            for (int j = 0; j < 8; ++j) {
                #pragma unroll
                for (int mm = 0; mm < 8; ++mm)
                    acc[j] = fmaf(Wsg[(size_t)(k0 + j) * IN_F + m0 + mm], wcol[mm], acc[j]);
            }
        }
        bf16x8 v;
        #pragma unroll
        for (int j = 0; j < 8; ++j) v[j] = f2bf(acc[j]);
        *reinterpret_cast<bf16x8*>(Fc + (size_t)c * 8) = v;
    } else {
        const float* src; short* dst; int N, KST, base;
        if      (cid < 4096)  { src = W1a; dst = F1a; N = 256; KST = 4; base = 0; }
        else if (cid < 6144)  { src = W1b; dst = F1b; N = 64;  KST = 8; base = 4096; }
        else                  { src = W2b; dst = F2b; N = 64;  KST = 8; base = 10240; }
        int c = cid - base;
        int lane = c & 63;
        int rem = c >> 6;
        int ks = rem % KST;
        int nt = rem / KST;
        int col = nt * 16 + (lane & 15);
        int k0 = ks * 32 + (lane >> 4) * 8;
        bf16x8 v;
        #pragma unroll
        for (int j = 0; j < 8; ++j)
            v[j] = f2bf(src[(size_t)(k0 + j) * N + col]);
        *reinterpret_cast<bf16x8*>(dst + (size_t)c * 8) = v;
    }
}

// ---------------------------------------------------------------------------
// build: fixed-stride bucket fill, 1 edge/thread (max TLP for latency-bound
// atomics). Runs alone (round-7 lesson: merging with streams costs 2-3x).
// cursor (zeroed by prep) ends up as deg.
// ---------------------------------------------------------------------------
__global__ __launch_bounds__(256) void build_kernel(
    const int* __restrict__ ei, int* __restrict__ cursor,
    unsigned short* __restrict__ esrc)
{
    int e = blockIdx.x * 256 + threadIdx.x;
    if (e >= N_EDGES) return;
    int src = ei[e];
    int dst = ei[N_EDGES + e];
    int p = atomicAdd(&cursor[dst], 1);
    if (p < SLOTS) esrc[(size_t)dst * SLOTS + p] = (unsigned short)src;
}

// ---------------------------------------------------------------------------
// LDS tile helpers: [16][C] bf16 with 16B-chunk XOR swizzle (chunk ^= row)
// ---------------------------------------------------------------------------
__device__ inline bf16x8 afrag_lds128(const short* S, int lane, int ks) {
    int row = lane & 15, g = lane >> 4;
    int chunk = (ks * 4 + g) ^ row;            // 0..15
    return *reinterpret_cast<const bf16x8*>(
        reinterpret_cast<const char*>(S) + row * 256 + chunk * 16);
}
__device__ inline bf16x8 afrag_lds256(const short* S, int lane, int ks) {
    int row = lane & 15, g = lane >> 4;
    int chunk = (ks * 4 + g) ^ row;            // XOR flips low 4 bits, 0..31
    return *reinterpret_cast<const bf16x8*>(
        reinterpret_cast<const char*>(S) + row * 512 + chunk * 16);
}

// ---------------------------------------------------------------------------
// Fused kernel (16 rows/block, 4 waves, LDS 20 KB, TWO barriers):
//   gather-mean -> Ms                       (zero-row padding, SALU indexing)
//   [issue branch1 A-frag loads]  sync
//   merged stage1: Hs1 = relu(x@W1a+b1a) || Hs2 = relu(Ms@Wc+b2a)
//       (two independent MFMA chains per nt; B-loads interleaved)  sync
//   merged stage2: o1 += Hs1@W1b || o2 += Hs2@W2b
//   out = o1 + o2 + b1b + b2b   (single guarded store)
// ---------------------------------------------------------------------------
__global__ __launch_bounds__(256) void fused_kernel(
    const short* __restrict__ xb, const unsigned short* __restrict__ esrc,
    const int* __restrict__ deg,
    const short* __restrict__ F1a, const float* __restrict__ b1a,
    const short* __restrict__ F1b, const float* __restrict__ b1b,
    const short* __restrict__ Fc,  const float* __restrict__ b2a,
    const short* __restrict__ F2b, const float* __restrict__ b2b,
    float* __restrict__ out)
{
    __shared__ short Ms[16 * 128];    // 4 KB
    __shared__ short Hs1[16 * 256];   // 8 KB
    __shared__ short Hs2[16 * 256];   // 8 KB
    const int t = threadIdx.x, w = t >> 6, lane = t & 63;
    const long r0 = (long)blockIdx.x * ROWS;
    const int row16 = lane & 15, g = lane >> 4;

    // ---- gather-mean: wave w owns rows w*4..+3; lane owns 2 features.
    //      16 row-loads in flight/chunk; padded slots read the zero row,
    //      so no per-feature masking; index math on the SALU pipe. ----
    #pragma unroll
    for (int nn = 0; nn < 4; ++nn) {
        int row = w * 4 + nn;
        long node = r0 + row;
        int d = min(deg[node], SLOTS);
        int du = __builtin_amdgcn_readfirstlane(d);  // wave-uniform
        int slot = min(lane, SLOTS - 1);
        int my = esrc[(size_t)node * SLOTS + slot];  // coalesced 2B/lane
        float ax = 0.f, ay = 0.f;
        for (int j = 0; j < du; j += 16) {
            unsigned u[16];
            #pragma unroll
            for (int k = 0; k < 16; ++k) {
                int idx = j + k;                      // <= 63 (du <= 56)
                int s = (idx < du) ? __builtin_amdgcn_readlane(my, idx)
                                   : ZERO_ROW;        // SALU cselect
                u[k] = *reinterpret_cast<const unsigned*>(
                    xb + (size_t)s * IN_F + lane * 2);
            }
            #pragma unroll
            for (int k = 0; k < 16; ++k) {
                ax += bflo(u[k]);                     // padded rows add 0
                ay += bfhi(u[k]);
            }
        }
        float inv = (du > 0) ? 1.0f / (float)du : 0.0f;
        ax *= inv; ay *= inv;
        int chunk = (lane >> 2) ^ row;                // XOR swizzle
        unsigned packed = (unsigned)(unsigned short)f2bf(ax)
                        | ((unsigned)(unsigned short)f2bf(ay) << 16);
        *reinterpret_cast<unsigned*>(reinterpret_cast<char*>(Ms)
            + row * 256 + chunk * 16 + (lane & 3) * 4) = packed;
    }

    // ---- issue branch1 A-frag loads BEFORE the barrier (latency hides) ----
    bf16x8 afrA[4];
    {
        const short* xrow = xb + (size_t)(r0 + row16) * IN_F + g * 8;
        #pragma unroll
        for (int ks = 0; ks < 4; ++ks)
            afrA[ks] = *reinterpret_cast<const bf16x8*>(xrow + ks * 32);
    }
    __syncthreads();

    // ---- merged stage1: two independent MFMA chains per nt ----
    bf16x8 afrB[4];
    #pragma unroll
    for (int ks = 0; ks < 4; ++ks) afrB[ks] = afrag_lds128(Ms, lane, ks);
    #pragma unroll
    for (int i = 0; i < 4; ++i) {
        int nt = w * 4 + i;
        bf16x8 bA[4], bB[4];
        #pragma unroll
        for (int ks = 0; ks < 4; ++ks) {
            bA[ks] = *reinterpret_cast<const bf16x8*>(
                F1a + ((size_t)(nt * 4 + ks) * 64 + lane) * 8);
            bB[ks] = *reinterpret_cast<const bf16x8*>(
                Fc + ((size_t)(nt * 4 + ks) * 64 + lane) * 8);
        }
        f32x4 acc1 = {0.f, 0.f, 0.f, 0.f};
        f32x4 acc2 = {0.f, 0.f, 0.f, 0.f};
        #pragma unroll
        for (int ks = 0; ks < 4; ++ks) {
            acc1 = __builtin_amdgcn_mfma_f32_16x16x32_bf16(afrA[ks], bA[ks], acc1, 0, 0, 0);
            acc2 = __builtin_amdgcn_mfma_f32_16x16x32_bf16(afrB[ks], bB[ks], acc2, 0, 0, 0);
        }
        int col = nt * 16 + row16;
        float bias1 = b1a[col], bias2 = b2a[col];
        #pragma unroll
        for (int reg = 0; reg < 4; ++reg) {
            int hrow = g * 4 + reg;
            int off = hrow * 512 + ((((col >> 3) ^ hrow) & 31) * 16) + (col & 7) * 2;
            *reinterpret_cast<short*>(reinterpret_cast<char*>(Hs1) + off)
                = f2bf(fmaxf(acc1[reg] + bias1, 0.0f));
            *reinterpret_cast<short*>(reinterpret_cast<char*>(Hs2) + off)
                = f2bf(fmaxf(acc2[reg] + bias2, 0.0f));
        }
    }
    __syncthreads();

    // ---- merged stage2: two independent accumulator chains ----
    f32x4 o1 = {0.f, 0.f, 0.f, 0.f};
    f32x4 o2 = {0.f, 0.f, 0.f, 0.f};
    #pragma unroll
    for (int ks = 0; ks < 8; ++ks) {
        bf16x8 a1 = afrag_lds256(Hs1, lane, ks);
        bf16x8 b1 = *reinterpret_cast<const bf16x8*>(
            F1b + ((size_t)(w * 8 + ks) * 64 + lane) * 8);
        o1 = __builtin_amdgcn_mfma_f32_16x16x32_bf16(a1, b1, o1, 0, 0, 0);
        bf16x8 a2 = afrag_lds256(Hs2, lane, ks);
        bf16x8 b2 = *reinterpret_cast<const bf16x8*>(
            F2b + ((size_t)(w * 8 + ks) * 64 + lane) * 8);
        o2 = __builtin_amdgcn_mfma_f32_16x16x32_bf16(a2, b2, o2, 0, 0, 0);
    }
    {
        int col = w * 16 + row16;
        float bias = b1b[col] + b2b[col];
        #pragma unroll
        for (int reg = 0; reg < 4; ++reg) {
            long row = r0 + g * 4 + reg;
            if (row < N_NODES)
                out[row * OUT_F + col] = o1[reg] + o2[reg] + bias;
        }
    }
}

// ---------------------------------------------------------------------------
extern "C" void kernel_launch(void* const* d_in, const int* in_sizes, int n_in,
                              void* d_out, int out_size, void* d_ws, size_t ws_size,
                              hipStream_t stream)
{
    const float* x   = (const float*)d_in[0];
    const int*   ei  = (const int*)d_in[1];
    const float* Wsg = (const float*)d_in[2];
    const float* W1a = (const float*)d_in[3];
    const float* b1a = (const float*)d_in[4];
    const float* W1b = (const float*)d_in[5];
    const float* b1b = (const float*)d_in[6];
    const float* W2a = (const float*)d_in[7];
    const float* b2a = (const float*)d_in[8];
    const float* W2b = (const float*)d_in[9];
    const float* b2b = (const float*)d_in[10];
    float* out = (float*)d_out;

    // workspace layout (all 16B-aligned): ~18.8 MB total
    int* cursor = (int*)d_ws;                              // [N_PAD] (200 KB)
    unsigned short* esrc = (unsigned short*)(cursor + N_PAD);  // [N_PAD*56] = 5.6 MB
    short* F1a = (short*)(esrc + (size_t)N_PAD * SLOTS);   // 4096 chunks (64 KB)
    short* F1b = F1a + 4096 * 8;                           // 2048 chunks (32 KB)
    short* Fc  = F1b + 2048 * 8;                           // 4096 chunks (64 KB)
    short* F2b = Fc + 4096 * 8;                            // 2048 chunks (32 KB)
    short* xb  = F2b + 2048 * 8;                           // [N_PAD*128] bf16 (12.8 MB)

    prep_kernel<<<3203, 256, 0, stream>>>(x, xb, Wsg, W2a, W1a, W1b, W2b,
                                          F1a, F1b, Fc, F2b, cursor);
    build_kernel<<<(N_EDGES + 255) / 256, 256, 0, stream>>>(ei, cursor, esrc);
    fused_kernel<<<NBLK, 256, 0, stream>>>(xb, esrc, cursor,
                                           F1a, b1a, F1b, b1b,
                                           Fc, b2a, F2b, b2b, out);
}